// Round 1
// baseline (240.121 us; speedup 1.0000x reference)
//
#include <hip/hip_runtime.h>

#define T_TOK 1024
#define H_DIM 1024
#define I_DIM 768
#define E_NUM 8
#define BK 32
#define LDS_STRIDE 40   // 32 + 8 pad: 2-way LDS bank aliasing only (free)
#define GU_STRIDE 130   // epilogue scratch stride (conflict-spread)

typedef __bf16 bf16x8 __attribute__((ext_vector_type(8)));
typedef float  f32x4  __attribute__((ext_vector_type(4)));

__device__ inline unsigned short f2bf(float f) {
    union { float f; unsigned u; } v; v.f = f;
    unsigned r = v.u + 0x7fffu + ((v.u >> 16) & 1u);
    return (unsigned short)(r >> 16);
}

// ---------------- init: zero out + counts (kernel, graph-capture safe) ----
__global__ void init_kernel(float* __restrict__ out, int* __restrict__ counts) {
    size_t i = (size_t)blockIdx.x * blockDim.x + threadIdx.x;
    ((float4*)out)[i] = make_float4(0.f, 0.f, 0.f, 0.f);
    if (i < E_NUM) counts[i] = 0;
}

// ---------------- router: top-2 of 8, renormalized weights ----------------
__global__ void router_kernel(const float* __restrict__ logits,
                              int* __restrict__ counts,
                              int* __restrict__ tok_list,
                              float* __restrict__ wt_list) {
    int t = blockIdx.x * blockDim.x + threadIdx.x;
    if (t >= T_TOK) return;
    float l[E_NUM];
#pragma unroll
    for (int e = 0; e < E_NUM; e++) l[e] = logits[t * E_NUM + e];
    int e0 = 0; float m0 = l[0];
#pragma unroll
    for (int e = 1; e < E_NUM; e++) if (l[e] > m0) { m0 = l[e]; e0 = e; }
    int e1 = -1; float m1 = -3e38f;
#pragma unroll
    for (int e = 0; e < E_NUM; e++) if (e != e0 && l[e] > m1) { m1 = l[e]; e1 = e; }
    // softmax + top2 + renorm == softmax over the two top logits
    float w0 = 1.0f / (1.0f + expf(m1 - m0));
    float w1 = 1.0f - w0;
    int p0 = atomicAdd(&counts[e0], 1);
    tok_list[e0 * T_TOK + p0] = t;
    wt_list[e0 * T_TOK + p0] = w0;
    int p1 = atomicAdd(&counts[e1], 1);
    tok_list[e1 * T_TOK + p1] = t;
    wt_list[e1 * T_TOK + p1] = w1;
}

// ---------------- exclusive scan of counts (E=8, trivial) -----------------
__global__ void scan_kernel(const int* __restrict__ counts, int* __restrict__ base) {
    if (threadIdx.x == 0) {
        int s = 0;
        for (int e = 0; e < E_NUM; e++) { base[e] = s; s += counts[e]; }
    }
}

// ---------------- GEMM1: gate_up = x_gathered @ dequant(w13)^T, + SiLU ----
// tile: M=64 tokens x (64 gate cols + 64 matching up cols), K-step 32
__global__ __launch_bounds__(256, 2) void gemm1_kernel(
    const float* __restrict__ x,
    const float* __restrict__ w13,
    const float* __restrict__ w13s,
    const int* __restrict__ counts,
    const int* __restrict__ base,
    const int* __restrict__ tok_list,
    unsigned short* __restrict__ act)   // [sum counts][768] bf16, grouped by expert
{
    const int e = blockIdx.z;
    const int count = counts[e];
    const int m0 = blockIdx.y * 64;
    if (m0 >= count) return;
    const int n0 = blockIdx.x * 64;     // gate-col base (0..704)
    const int abase = base[e];

    __shared__ union {
        struct {
            unsigned short As[64 * LDS_STRIDE];
            unsigned short Bs[128 * LDS_STRIDE];
        } s;
        float gu[64 * GU_STRIDE];
    } u;
    __shared__ int tokS[64];

    const int tid = threadIdx.x;
    if (tid < 64) {
        int r = m0 + tid;
        tokS[tid] = (r < count) ? tok_list[e * T_TOK + r] : 0;
    }
    __syncthreads();

    const int wid  = tid >> 6;
    const int lane = tid & 63;
    const int lrow = lane & 15;
    const int quad = lane >> 4;
    const int wm = wid >> 1;            // 0..1: 32-row half
    const int wn = wid & 1;             // 0..1: 64-col half

    f32x4 acc[2][4];
#pragma unroll
    for (int i = 0; i < 2; i++)
#pragma unroll
        for (int j = 0; j < 4; j++) { f32x4 z = {0.f,0.f,0.f,0.f}; acc[i][j] = z; }

    for (int k0 = 0; k0 < H_DIM; k0 += BK) {
        // stage A: 64 rows x 32 fp32 -> bf16 (512 float4, 2/thread)
#pragma unroll
        for (int i = 0; i < 2; i++) {
            int q = i * 256 + tid;
            int row = q >> 3, c4 = q & 7;
            const float4 v = *(const float4*)(x + (size_t)tokS[row] * H_DIM + k0 + c4 * 4);
            ushort4 b;
            b.x = f2bf(v.x); b.y = f2bf(v.y); b.z = f2bf(v.z); b.w = f2bf(v.w);
            *(ushort4*)&u.s.As[row * LDS_STRIDE + c4 * 4] = b;
        }
        // stage B: 128 rows (64 gate + 64 up) x 32 fp32, dequant -> bf16
#pragma unroll
        for (int i = 0; i < 4; i++) {
            int q = i * 256 + tid;
            int row = q >> 3, c4 = q & 7;
            int ng = (row < 64) ? (n0 + row) : (I_DIM + n0 + row - 64);
            size_t widx = (size_t)e * (2 * I_DIM) + ng;
            float s = w13s[widx * (H_DIM / 128) + (k0 >> 7)];
            const float4 v = *(const float4*)(w13 + widx * H_DIM + k0 + c4 * 4);
            ushort4 b;
            b.x = f2bf(v.x * s); b.y = f2bf(v.y * s);
            b.z = f2bf(v.z * s); b.w = f2bf(v.w * s);
            *(ushort4*)&u.s.Bs[row * LDS_STRIDE + c4 * 4] = b;
        }
        __syncthreads();

        bf16x8 af[2], bfr[4];
#pragma unroll
        for (int i = 0; i < 2; i++)
            af[i] = *(const bf16x8*)&u.s.As[(wm * 32 + i * 16 + lrow) * LDS_STRIDE + quad * 8];
#pragma unroll
        for (int j = 0; j < 4; j++)
            bfr[j] = *(const bf16x8*)&u.s.Bs[(wn * 64 + j * 16 + lrow) * LDS_STRIDE + quad * 8];
#pragma unroll
        for (int i = 0; i < 2; i++)
#pragma unroll
            for (int j = 0; j < 4; j++)
                acc[i][j] = __builtin_amdgcn_mfma_f32_16x16x32_bf16(af[i], bfr[j], acc[i][j], 0, 0, 0);
        __syncthreads();
    }

    // gate_up -> LDS (reuse staging LDS; last sync above protects it)
#pragma unroll
    for (int i = 0; i < 2; i++)
#pragma unroll
        for (int j = 0; j < 4; j++)
#pragma unroll
            for (int r = 0; r < 4; r++) {
                int m = wm * 32 + i * 16 + quad * 4 + r;
                int c = wn * 64 + j * 16 + lrow;
                u.gu[m * GU_STRIDE + c] = acc[i][j][r];
            }
    __syncthreads();

    // act = silu(gate) * up, store bf16 (16 elems/thread)
#pragma unroll
    for (int ii = 0; ii < 16; ii++) {
        int o = ii * 256 + tid;
        int m = o >> 6, c = o & 63;
        if (m0 + m < count) {
            float g  = u.gu[m * GU_STRIDE + c];
            float up = u.gu[m * GU_STRIDE + 64 + c];
            float a  = g / (1.0f + expf(-g)) * up;
            act[((size_t)(abase + m0 + m)) * I_DIM + n0 + c] = f2bf(a);
        }
    }
}

// ---------------- GEMM2: out += combine_w * (act @ dequant(w2)^T) ---------
// tile: M=64 rows x N=64 h-cols, K=768, K-step 32
__global__ __launch_bounds__(256, 2) void gemm2_kernel(
    const unsigned short* __restrict__ act,
    const float* __restrict__ w2,
    const float* __restrict__ w2s,
    const int* __restrict__ counts,
    const int* __restrict__ base,
    const int* __restrict__ tok_list,
    const float* __restrict__ wt_list,
    float* __restrict__ out)
{
    const int e = blockIdx.z;
    const int count = counts[e];
    const int m0 = blockIdx.y * 64;
    if (m0 >= count) return;
    const int n0 = blockIdx.x * 64;     // h base
    const int abase = base[e];

    __shared__ unsigned short As[64 * LDS_STRIDE];
    __shared__ unsigned short Bs[64 * LDS_STRIDE];
    __shared__ int   tokS[64];
    __shared__ float wtS[64];

    const int tid = threadIdx.x;
    if (tid < 64) {
        int r = m0 + tid;
        tokS[tid] = (r < count) ? tok_list[e * T_TOK + r] : 0;
        wtS[tid]  = (r < count) ? wt_list[e * T_TOK + r] : 0.f;
    }
    __syncthreads();

    const int wid  = tid >> 6;
    const int lane = tid & 63;
    const int lrow = lane & 15;
    const int quad = lane >> 4;
    const int wm = wid >> 1;
    const int wn = wid & 1;

    f32x4 acc[2][2];
#pragma unroll
    for (int i = 0; i < 2; i++)
#pragma unroll
        for (int j = 0; j < 2; j++) { f32x4 z = {0.f,0.f,0.f,0.f}; acc[i][j] = z; }

    for (int k0 = 0; k0 < I_DIM; k0 += BK) {
        // stage A: 64 rows x 32 bf16 (already bf16): 256 x 16B, 1/thread
        {
            int row = tid >> 2, c = tid & 3;
            int rg = m0 + row;
            uint4 v = make_uint4(0u, 0u, 0u, 0u);
            if (rg < count)
                v = *(const uint4*)(act + ((size_t)(abase + rg)) * I_DIM + k0 + c * 8);
            *(uint4*)&As[row * LDS_STRIDE + c * 8] = v;
        }
        // stage B: 64 rows x 32 fp32, dequant -> bf16 (512 float4, 2/thread)
#pragma unroll
        for (int i = 0; i < 2; i++) {
            int q = i * 256 + tid;
            int row = q >> 3, c4 = q & 7;
            int hg = n0 + row;
            size_t widx = (size_t)e * H_DIM + hg;
            float s = w2s[widx * (I_DIM / 128) + (k0 >> 7)];
            const float4 v = *(const float4*)(w2 + widx * I_DIM + k0 + c4 * 4);
            ushort4 b;
            b.x = f2bf(v.x * s); b.y = f2bf(v.y * s);
            b.z = f2bf(v.z * s); b.w = f2bf(v.w * s);
            *(ushort4*)&Bs[row * LDS_STRIDE + c4 * 4] = b;
        }
        __syncthreads();

        bf16x8 af[2], bfr[2];
#pragma unroll
        for (int i = 0; i < 2; i++)
            af[i] = *(const bf16x8*)&As[(wm * 32 + i * 16 + lrow) * LDS_STRIDE + quad * 8];
#pragma unroll
        for (int j = 0; j < 2; j++)
            bfr[j] = *(const bf16x8*)&Bs[(wn * 32 + j * 16 + lrow) * LDS_STRIDE + quad * 8];
#pragma unroll
        for (int i = 0; i < 2; i++)
#pragma unroll
            for (int j = 0; j < 2; j++)
                acc[i][j] = __builtin_amdgcn_mfma_f32_16x16x32_bf16(af[i], bfr[j], acc[i][j], 0, 0, 0);
        __syncthreads();
    }

    // epilogue: weighted atomic scatter into out
#pragma unroll
    for (int i = 0; i < 2; i++)
#pragma unroll
        for (int j = 0; j < 2; j++)
#pragma unroll
            for (int r = 0; r < 4; r++) {
                int m = wm * 32 + i * 16 + quad * 4 + r;
                if (m0 + m < count) {
                    int h = n0 + wn * 32 + j * 16 + lrow;
                    atomicAdd(&out[(size_t)tokS[m] * H_DIM + h], wtS[m] * acc[i][j][r]);
                }
            }
}

extern "C" void kernel_launch(void* const* d_in, const int* in_sizes, int n_in,
                              void* d_out, int out_size, void* d_ws, size_t ws_size,
                              hipStream_t stream) {
    (void)in_sizes; (void)n_in; (void)out_size; (void)ws_size;
    const float* x      = (const float*)d_in[0];
    const float* logits = (const float*)d_in[1];
    const float* w13    = (const float*)d_in[2];
    const float* w13s   = (const float*)d_in[3];
    const float* w2     = (const float*)d_in[4];
    const float* w2s    = (const float*)d_in[5];
    float* out = (float*)d_out;

    char* ws = (char*)d_ws;
    int*   counts   = (int*)ws;                       // 32 B   @ 0
    int*   base     = (int*)(ws + 128);               // 32 B   @ 128
    int*   tok_list = (int*)(ws + 256);               // 32 KB  @ 256
    float* wt_list  = (float*)(ws + 256 + 32768);     // 32 KB
    unsigned short* act = (unsigned short*)(ws + 256 + 65536);  // 2048*768*2 = 3 MB

    // zero out + counts (kernels only: graph-capture safe)
    init_kernel<<<dim3((T_TOK * H_DIM) / (256 * 4)), 256, 0, stream>>>(out, counts);
    router_kernel<<<dim3(T_TOK / 256), 256, 0, stream>>>(logits, counts, tok_list, wt_list);
    scan_kernel<<<dim3(1), 64, 0, stream>>>(counts, base);
    gemm1_kernel<<<dim3(I_DIM / 64, T_TOK / 64, E_NUM), 256, 0, stream>>>(
        x, w13, w13s, counts, base, tok_list, act);
    gemm2_kernel<<<dim3(H_DIM / 64, T_TOK / 64, E_NUM), 256, 0, stream>>>(
        act, w2, w2s, counts, base, tok_list, wt_list, out);
}

// Round 2
// 195.390 us; speedup vs baseline: 1.2289x; 1.2289x over previous
//
#include <hip/hip_runtime.h>

#define T_TOK 1024
#define H_DIM 1024
#define I_DIM 768
#define E_NUM 8

typedef __bf16 bf16x8 __attribute__((ext_vector_type(8)));
typedef float  f32x4  __attribute__((ext_vector_type(4)));

__device__ inline void store_bf16x8(void* dst, float4 a, float4 b) {
    bf16x8 r;
    r[0] = (__bf16)a.x; r[1] = (__bf16)a.y; r[2] = (__bf16)a.z; r[3] = (__bf16)a.w;
    r[4] = (__bf16)b.x; r[5] = (__bf16)b.y; r[6] = (__bf16)b.z; r[7] = (__bf16)b.w;
    *(bf16x8*)dst = r;
}

__device__ inline void store_bf16x8_scaled(void* dst, float4 a, float4 b, float s) {
    bf16x8 r;
    r[0] = (__bf16)(a.x * s); r[1] = (__bf16)(a.y * s);
    r[2] = (__bf16)(a.z * s); r[3] = (__bf16)(a.w * s);
    r[4] = (__bf16)(b.x * s); r[5] = (__bf16)(b.y * s);
    r[6] = (__bf16)(b.z * s); r[7] = (__bf16)(b.w * s);
    *(bf16x8*)dst = r;
}

// ---------------- init: zero out + counts ---------------------------------
__global__ void init_kernel(float* __restrict__ out, int* __restrict__ counts) {
    size_t i = (size_t)blockIdx.x * blockDim.x + threadIdx.x;
    ((float4*)out)[i] = make_float4(0.f, 0.f, 0.f, 0.f);
    if (i < E_NUM) counts[i] = 0;
}

// ---------------- router: top-2 of 8, renormalized weights ----------------
__global__ void router_kernel(const float* __restrict__ logits,
                              int* __restrict__ counts,
                              int* __restrict__ tok_list,
                              float* __restrict__ wt_list) {
    int t = blockIdx.x * blockDim.x + threadIdx.x;
    if (t >= T_TOK) return;
    float l[E_NUM];
#pragma unroll
    for (int e = 0; e < E_NUM; e++) l[e] = logits[t * E_NUM + e];
    int e0 = 0; float m0 = l[0];
#pragma unroll
    for (int e = 1; e < E_NUM; e++) if (l[e] > m0) { m0 = l[e]; e0 = e; }
    int e1 = -1; float m1 = -3e38f;
#pragma unroll
    for (int e = 0; e < E_NUM; e++) if (e != e0 && l[e] > m1) { m1 = l[e]; e1 = e; }
    float w0 = 1.0f / (1.0f + expf(m1 - m0));
    float w1 = 1.0f - w0;
    int p0 = atomicAdd(&counts[e0], 1);
    tok_list[e0 * T_TOK + p0] = t;
    wt_list[e0 * T_TOK + p0] = w0;
    int p1 = atomicAdd(&counts[e1], 1);
    tok_list[e1 * T_TOK + p1] = t;
    wt_list[e1 * T_TOK + p1] = w1;
}

// ---------------- exclusive scan of counts (E=8) --------------------------
__global__ void scan_kernel(const int* __restrict__ counts, int* __restrict__ base) {
    if (threadIdx.x == 0) {
        int s = 0;
        for (int e = 0; e < E_NUM; e++) { base[e] = s; s += counts[e]; }
    }
}

// ---------------- GEMM1: gate_up = x_g @ dq(w13)^T, + SiLU ----------------
// tile M=32 tokens x (64 gate + 64 up cols), BK=64, reg-prefetch pipeline
__global__ __launch_bounds__(256, 3) void gemm1_kernel(
    const float* __restrict__ x,
    const float* __restrict__ w13,
    const float* __restrict__ w13s,
    const int* __restrict__ counts,
    const int* __restrict__ base,
    const int* __restrict__ tok_list,
    __bf16* __restrict__ act)
{
    const int e = blockIdx.z;
    const int count = counts[e];
    const int m0 = blockIdx.y * 32;
    if (m0 >= count) return;
    const int n0 = blockIdx.x * 64;
    const int abase = base[e];

    __shared__ union {
        struct {
            unsigned short As[32 * 64];   // 4 KB   (row stride 64 bf16 = 128B)
            unsigned short Bs[128 * 64];  // 16 KB
        } s;
        float gu[32 * 132];               // epilogue scratch
    } u;
    __shared__ int tokS[32];

    const int tid = threadIdx.x;
    if (tid < 32) {
        int r = m0 + tid;
        tokS[tid] = (r < count) ? tok_list[e * T_TOK + r] : tok_list[e * T_TOK];
    }
    __syncthreads();

    // staging geometry (XOR-swizzled granule columns)
    const int srow = tid >> 3;          // 0..31
    const int scol = tid & 7;           // logical 16B-granule column
    const int sApos = srow * 64 + ((scol ^ (srow & 7)) * 8);
    const float* pA = x + (size_t)tokS[srow] * H_DIM + scol * 8;

    const float* pB[4];
    int sBpos[4], sIdx[4];
#pragma unroll
    for (int i = 0; i < 4; i++) {
        int brow = srow + 32 * i;       // 0..127
        int ng = (brow < 64) ? (n0 + brow) : (I_DIM + n0 + brow - 64);
        size_t widx = (size_t)e * (2 * I_DIM) + ng;
        pB[i] = w13 + widx * H_DIM + scol * 8;
        sIdx[i] = (int)(widx * (H_DIM / 128));
        sBpos[i] = brow * 64 + ((scol ^ (brow & 7)) * 8);
    }

    const int lane = tid & 63;
    const int wid  = tid >> 6;
    const int lrow = lane & 15;
    const int quad = lane >> 4;

    f32x4 acc[2][2];
#pragma unroll
    for (int i = 0; i < 2; i++)
#pragma unroll
        for (int j = 0; j < 2; j++) { f32x4 z = {0.f, 0.f, 0.f, 0.f}; acc[i][j] = z; }

    float4 ra0, ra1, rb0[4], rb1[4];
    float sb[4];
    ra0 = *(const float4*)(pA);
    ra1 = *(const float4*)(pA + 4);
#pragma unroll
    for (int i = 0; i < 4; i++) {
        rb0[i] = *(const float4*)(pB[i]);
        rb1[i] = *(const float4*)(pB[i] + 4);
        sb[i] = w13s[sIdx[i]];
    }

    for (int it = 0; it < H_DIM / 64; ++it) {
        __syncthreads();   // previous iter's ds_reads done
        store_bf16x8(&u.s.As[sApos], ra0, ra1);
#pragma unroll
        for (int i = 0; i < 4; i++)
            store_bf16x8_scaled(&u.s.Bs[sBpos[i]], rb0[i], rb1[i], sb[i]);
        __syncthreads();

        if (it + 1 < H_DIM / 64) {     // prefetch next K-step (overlaps MFMA below)
            int k = (it + 1) * 64;
            ra0 = *(const float4*)(pA + k);
            ra1 = *(const float4*)(pA + k + 4);
#pragma unroll
            for (int i = 0; i < 4; i++) {
                rb0[i] = *(const float4*)(pB[i] + k);
                rb1[i] = *(const float4*)(pB[i] + k + 4);
                sb[i] = w13s[sIdx[i] + (k >> 7)];
            }
        }

#pragma unroll
        for (int kk = 0; kk < 2; kk++) {
            const int xc = ((kk * 4 + quad) ^ (lrow & 7)) * 8;
            bf16x8 a0 = *(const bf16x8*)&u.s.As[lrow * 64 + xc];
            bf16x8 a1 = *(const bf16x8*)&u.s.As[(16 + lrow) * 64 + xc];
            bf16x8 b0 = *(const bf16x8*)&u.s.Bs[(wid * 32 + lrow) * 64 + xc];
            bf16x8 b1 = *(const bf16x8*)&u.s.Bs[(wid * 32 + 16 + lrow) * 64 + xc];
            acc[0][0] = __builtin_amdgcn_mfma_f32_16x16x32_bf16(a0, b0, acc[0][0], 0, 0, 0);
            acc[0][1] = __builtin_amdgcn_mfma_f32_16x16x32_bf16(a0, b1, acc[0][1], 0, 0, 0);
            acc[1][0] = __builtin_amdgcn_mfma_f32_16x16x32_bf16(a1, b0, acc[1][0], 0, 0, 0);
            acc[1][1] = __builtin_amdgcn_mfma_f32_16x16x32_bf16(a1, b1, acc[1][1], 0, 0, 0);
        }
    }

    __syncthreads();   // staging LDS dead; reuse as gu
#pragma unroll
    for (int i = 0; i < 2; i++)
#pragma unroll
        for (int j = 0; j < 2; j++)
#pragma unroll
            for (int r = 0; r < 4; r++) {
                int m = i * 16 + quad * 4 + r;
                int c = wid * 32 + j * 16 + lrow;
                u.gu[m * 132 + c] = acc[i][j][r];
            }
    __syncthreads();

#pragma unroll
    for (int ii = 0; ii < 8; ii++) {
        int o = ii * 256 + tid;        // 0..2047
        int m = o >> 6, c = o & 63;
        if (m0 + m < count) {
            float g  = u.gu[m * 132 + c];
            float up = u.gu[m * 132 + 64 + c];
            float a  = g / (1.0f + expf(-g)) * up;
            act[(size_t)(abase + m0 + m) * I_DIM + n0 + c] = (__bf16)a;
        }
    }
}

// ---------------- GEMM2: out += w * (act @ dq(w2)^T) ----------------------
// tile M=32 x N=128 h-cols, BK=64, reg-prefetch pipeline
__global__ __launch_bounds__(256, 3) void gemm2_kernel(
    const __bf16* __restrict__ act,
    const float* __restrict__ w2,
    const float* __restrict__ w2s,
    const int* __restrict__ counts,
    const int* __restrict__ base,
    const int* __restrict__ tok_list,
    const float* __restrict__ wt_list,
    float* __restrict__ out)
{
    const int e = blockIdx.z;
    const int count = counts[e];
    const int m0 = blockIdx.y * 32;
    if (m0 >= count) return;
    const int n0 = blockIdx.x * 128;
    const int abase = base[e];

    __shared__ unsigned short As[32 * 64];    // 4 KB
    __shared__ unsigned short Bs[128 * 64];   // 16 KB
    __shared__ int   tokS[32];
    __shared__ float wtS[32];

    const int tid = threadIdx.x;
    if (tid < 32) {
        int r = m0 + tid;
        tokS[tid] = (r < count) ? tok_list[e * T_TOK + r] : tok_list[e * T_TOK];
        wtS[tid]  = (r < count) ? wt_list[e * T_TOK + r] : 0.f;
    }
    __syncthreads();

    const int srow = tid >> 3;
    const int scol = tid & 7;
    const int sApos = srow * 64 + ((scol ^ (srow & 7)) * 8);
    int arow = m0 + srow; if (arow > count - 1) arow = count - 1;
    const unsigned short* pA =
        (const unsigned short*)act + (size_t)(abase + arow) * I_DIM + scol * 8;

    const float* pB[4];
    int sBpos[4], sIdx[4];
#pragma unroll
    for (int i = 0; i < 4; i++) {
        int brow = srow + 32 * i;             // 0..127 -> h col n0+brow
        size_t widx = (size_t)e * H_DIM + (n0 + brow);
        pB[i] = w2 + widx * I_DIM + scol * 8;
        sIdx[i] = (int)(widx * (I_DIM / 128));
        sBpos[i] = brow * 64 + ((scol ^ (brow & 7)) * 8);
    }

    const int lane = tid & 63;
    const int wid  = tid >> 6;
    const int lrow = lane & 15;
    const int quad = lane >> 4;

    f32x4 acc[2][2];
#pragma unroll
    for (int i = 0; i < 2; i++)
#pragma unroll
        for (int j = 0; j < 2; j++) { f32x4 z = {0.f, 0.f, 0.f, 0.f}; acc[i][j] = z; }

    uint4 raa;
    float4 rb0[4], rb1[4];
    float sb[4];
    raa = *(const uint4*)(pA);
#pragma unroll
    for (int i = 0; i < 4; i++) {
        rb0[i] = *(const float4*)(pB[i]);
        rb1[i] = *(const float4*)(pB[i] + 4);
        sb[i] = w2s[sIdx[i]];
    }

    for (int it = 0; it < I_DIM / 64; ++it) {
        __syncthreads();
        *(uint4*)&As[sApos] = raa;
#pragma unroll
        for (int i = 0; i < 4; i++)
            store_bf16x8_scaled(&Bs[sBpos[i]], rb0[i], rb1[i], sb[i]);
        __syncthreads();

        if (it + 1 < I_DIM / 64) {
            int k = (it + 1) * 64;
            raa = *(const uint4*)(pA + k);
#pragma unroll
            for (int i = 0; i < 4; i++) {
                rb0[i] = *(const float4*)(pB[i] + k);
                rb1[i] = *(const float4*)(pB[i] + k + 4);
                sb[i] = w2s[sIdx[i] + (k >> 7)];
            }
        }

#pragma unroll
        for (int kk = 0; kk < 2; kk++) {
            const int xc = ((kk * 4 + quad) ^ (lrow & 7)) * 8;
            bf16x8 a0 = *(const bf16x8*)&As[lrow * 64 + xc];
            bf16x8 a1 = *(const bf16x8*)&As[(16 + lrow) * 64 + xc];
            bf16x8 b0 = *(const bf16x8*)&Bs[(wid * 32 + lrow) * 64 + xc];
            bf16x8 b1 = *(const bf16x8*)&Bs[(wid * 32 + 16 + lrow) * 64 + xc];
            acc[0][0] = __builtin_amdgcn_mfma_f32_16x16x32_bf16(a0, b0, acc[0][0], 0, 0, 0);
            acc[0][1] = __builtin_amdgcn_mfma_f32_16x16x32_bf16(a0, b1, acc[0][1], 0, 0, 0);
            acc[1][0] = __builtin_amdgcn_mfma_f32_16x16x32_bf16(a1, b0, acc[1][0], 0, 0, 0);
            acc[1][1] = __builtin_amdgcn_mfma_f32_16x16x32_bf16(a1, b1, acc[1][1], 0, 0, 0);
        }
    }

    // weighted atomic scatter
#pragma unroll
    for (int i = 0; i < 2; i++)
#pragma unroll
        for (int j = 0; j < 2; j++)
#pragma unroll
            for (int r = 0; r < 4; r++) {
                int m = i * 16 + quad * 4 + r;
                if (m0 + m < count) {
                    int h = n0 + wid * 32 + j * 16 + lrow;
                    atomicAdd(&out[(size_t)tokS[m] * H_DIM + h], wtS[m] * acc[i][j][r]);
                }
            }
}

extern "C" void kernel_launch(void* const* d_in, const int* in_sizes, int n_in,
                              void* d_out, int out_size, void* d_ws, size_t ws_size,
                              hipStream_t stream) {
    (void)in_sizes; (void)n_in; (void)out_size; (void)ws_size;
    const float* x      = (const float*)d_in[0];
    const float* logits = (const float*)d_in[1];
    const float* w13    = (const float*)d_in[2];
    const float* w13s   = (const float*)d_in[3];
    const float* w2     = (const float*)d_in[4];
    const float* w2s    = (const float*)d_in[5];
    float* out = (float*)d_out;

    char* ws = (char*)d_ws;
    int*   counts   = (int*)ws;
    int*   base     = (int*)(ws + 128);
    int*   tok_list = (int*)(ws + 256);
    float* wt_list  = (float*)(ws + 256 + 32768);
    __bf16* act     = (__bf16*)(ws + 256 + 65536);   // 2048*768*2 = 3 MB

    init_kernel<<<dim3((T_TOK * H_DIM) / (256 * 4)), 256, 0, stream>>>(out, counts);
    router_kernel<<<dim3(T_TOK / 256), 256, 0, stream>>>(logits, counts, tok_list, wt_list);
    scan_kernel<<<dim3(1), 64, 0, stream>>>(counts, base);
    gemm1_kernel<<<dim3(I_DIM / 64, T_TOK / 32, E_NUM), 256, 0, stream>>>(
        x, w13, w13s, counts, base, tok_list, act);
    gemm2_kernel<<<dim3(H_DIM / 128, T_TOK / 32, E_NUM), 256, 0, stream>>>(
        act, w2, w2s, counts, base, tok_list, wt_list, out);
}

// Round 3
// 189.806 us; speedup vs baseline: 1.2651x; 1.0294x over previous
//
#include <hip/hip_runtime.h>

#define T_TOK 1024
#define H_DIM 1024
#define I_DIM 768
#define E_NUM 8

typedef __bf16 bf16x8 __attribute__((ext_vector_type(8)));
typedef __bf16 bf16x4 __attribute__((ext_vector_type(4)));
typedef float  f32x4  __attribute__((ext_vector_type(4)));

__device__ inline void gl2lds16(const void* g, void* l) {
    __builtin_amdgcn_global_load_lds(
        (const __attribute__((address_space(1))) unsigned int*)g,
        (__attribute__((address_space(3))) unsigned int*)l, 16, 0, 0);
}

// ---- init: zero out, zero counts, convert x fp32->bf16 -------------------
__global__ void init_kernel(float4* __restrict__ out4, int* __restrict__ counts,
                            const float4* __restrict__ x4, bf16x4* __restrict__ xbf4) {
    int i = blockIdx.x * 256 + threadIdx.x;          // grid 1024 -> i < 262144
    out4[i] = make_float4(0.f, 0.f, 0.f, 0.f);
    if (i < E_NUM) counts[i] = 0;
    float4 v = x4[i];
    bf16x4 b;
    b[0] = (__bf16)v.x; b[1] = (__bf16)v.y; b[2] = (__bf16)v.z; b[3] = (__bf16)v.w;
    xbf4[i] = b;
}

// ---- router: top-2 of 8, renormalized weights ----------------------------
__global__ void router_kernel(const float* __restrict__ logits,
                              int* __restrict__ counts,
                              int* __restrict__ tok_list,
                              float* __restrict__ wt_list) {
    int t = blockIdx.x * blockDim.x + threadIdx.x;
    if (t >= T_TOK) return;
    float l[E_NUM];
#pragma unroll
    for (int e = 0; e < E_NUM; e++) l[e] = logits[t * E_NUM + e];
    int e0 = 0; float m0 = l[0];
#pragma unroll
    for (int e = 1; e < E_NUM; e++) if (l[e] > m0) { m0 = l[e]; e0 = e; }
    int e1 = -1; float m1 = -3e38f;
#pragma unroll
    for (int e = 0; e < E_NUM; e++) if (e != e0 && l[e] > m1) { m1 = l[e]; e1 = e; }
    float w0 = 1.0f / (1.0f + expf(m1 - m0));
    float w1 = 1.0f - w0;
    int p0 = atomicAdd(&counts[e0], 1);
    tok_list[e0 * T_TOK + p0] = t;
    wt_list[e0 * T_TOK + p0] = w0;
    int p1 = atomicAdd(&counts[e1], 1);
    tok_list[e1 * T_TOK + p1] = t;
    wt_list[e1 * T_TOK + p1] = w1;
}

__global__ void scan_kernel(const int* __restrict__ counts, int* __restrict__ base) {
    if (threadIdx.x == 0) {
        int s = 0;
        for (int e = 0; e < E_NUM; e++) { base[e] = s; s += counts[e]; }
    }
}

// ---- GEMM1: act = silu(gate)*up, gate_up = x_g @ dq(w13)^T ---------------
// M=32 x N=128(64 gate + 64 up), BK=32, async global_load_lds double-buffer
__global__ __launch_bounds__(256, 4) void gemm1_kernel(
    const __bf16* __restrict__ xbf,
    const float* __restrict__ w13,
    const float* __restrict__ w13s,
    const int* __restrict__ counts,
    const int* __restrict__ base,
    const int* __restrict__ tok_list,
    __bf16* __restrict__ act)
{
    const int e = blockIdx.z;
    const int count = counts[e];
    const int m0 = blockIdx.y * 32;
    if (m0 >= count) return;
    const int n0 = blockIdx.x * 64;
    const int abase = base[e];

    __shared__ union {
        struct {
            float  Bf[2][128 * 32];   // fp32 weights, row=128B, no pad (lane-linear)
            __bf16 Ab[2][32 * 32];    // bf16 x, row=64B
        } s;
        float gu[32 * 132];
    } u;
    __shared__ int tokS[32];

    const int tid = threadIdx.x;
    if (tid < 32) {
        int r = m0 + tid;
        tokS[tid] = (r < count) ? tok_list[e * T_TOK + r] : tok_list[e * T_TOK];
    }
    __syncthreads();

    const int wid = tid >> 6, lane = tid & 63, lrow = lane & 15, quad = lane >> 4;

    // scale prefetch: 2 B-rows per lane x 8 k-blocks
    const int rB0 = wid * 32 + lrow, rB1 = rB0 + 16;
    const size_t wi0 = (size_t)e * (2 * I_DIM) + ((rB0 < 64) ? n0 + rB0 : I_DIM + n0 + rB0 - 64);
    const size_t wi1 = (size_t)e * (2 * I_DIM) + ((rB1 < 64) ? n0 + rB1 : I_DIM + n0 + rB1 - 64);
    float sc0[8], sc1[8];
#pragma unroll
    for (int kb = 0; kb < 8; kb++) { sc0[kb] = w13s[wi0 * 8 + kb]; sc1[kb] = w13s[wi1 * 8 + kb]; }

    // staging source pointers (global-side XOR swizzle on 16B granules)
    const __bf16* pAst;
    {
        int r = (wid & 1) * 16 + (lane >> 2);
        int g = lane & 3;
        pAst = xbf + (size_t)tokS[r] * H_DIM + ((g ^ (r & 3)) << 3);
    }
    const float* pBst[4];
#pragma unroll
    for (int i8 = 0; i8 < 4; i8++) {
        int r = wid * 32 + i8 * 8 + (lane >> 3);
        int g = lane & 7;
        size_t wrow = (size_t)e * (2 * I_DIM) + ((r < 64) ? n0 + r : I_DIM + n0 + r - 64);
        pBst[i8] = w13 + wrow * H_DIM + ((g ^ (r & 7)) << 2);
    }

    // reader LDS byte offsets (swizzle-aware)
    const int aoff0 = (lrow * 32 + ((quad ^ (lrow & 3)) << 3)) * 2;
    const int aoff1 = ((16 + lrow) * 32 + ((quad ^ (lrow & 3)) << 3)) * 2;
    const int b0off0 = (rB0 * 32 + (((2 * quad)     ^ (lrow & 7)) << 2)) * 4;
    const int b0off1 = (rB0 * 32 + (((2 * quad + 1) ^ (lrow & 7)) << 2)) * 4;
    const int b1off0 = (rB1 * 32 + (((2 * quad)     ^ (lrow & 7)) << 2)) * 4;
    const int b1off1 = (rB1 * 32 + (((2 * quad + 1) ^ (lrow & 7)) << 2)) * 4;

    f32x4 acc[2][2];
#pragma unroll
    for (int i = 0; i < 2; i++)
#pragma unroll
        for (int j = 0; j < 2; j++) { f32x4 z = {0.f, 0.f, 0.f, 0.f}; acc[i][j] = z; }

    auto issue = [&](int b, int k0) {
        if (wid < 2)
            gl2lds16(pAst + k0, &u.s.Ab[b][(wid * 16) * 32]);
#pragma unroll
        for (int i8 = 0; i8 < 4; i8++)
            gl2lds16(pBst[i8] + k0, &u.s.Bf[b][(wid * 32 + i8 * 8) * 32]);
    };
    issue(0, 0);

#pragma unroll
    for (int kb = 0; kb < 8; ++kb) {
#pragma unroll
        for (int t = 0; t < 4; ++t) {
            const int it = kb * 4 + t, b = it & 1;
            __syncthreads();                       // drains vmcnt: buf b ready
            if (it < 31) issue(b ^ 1, (it + 1) * 32);
            const char* Abase = (const char*)u.s.Ab[b];
            const char* Bbase = (const char*)u.s.Bf[b];
            bf16x8 a0 = *(const bf16x8*)(Abase + aoff0);
            bf16x8 a1 = *(const bf16x8*)(Abase + aoff1);
            f32x4 p00 = *(const f32x4*)(Bbase + b0off0);
            f32x4 p01 = *(const f32x4*)(Bbase + b0off1);
            f32x4 p10 = *(const f32x4*)(Bbase + b1off0);
            f32x4 p11 = *(const f32x4*)(Bbase + b1off1);
            bf16x8 bf0, bf1;
#pragma unroll
            for (int v = 0; v < 4; v++) {
                bf0[v]     = (__bf16)(p00[v] * sc0[kb]);
                bf0[4 + v] = (__bf16)(p01[v] * sc0[kb]);
                bf1[v]     = (__bf16)(p10[v] * sc1[kb]);
                bf1[4 + v] = (__bf16)(p11[v] * sc1[kb]);
            }
            acc[0][0] = __builtin_amdgcn_mfma_f32_16x16x32_bf16(a0, bf0, acc[0][0], 0, 0, 0);
            acc[1][0] = __builtin_amdgcn_mfma_f32_16x16x32_bf16(a1, bf0, acc[1][0], 0, 0, 0);
            acc[0][1] = __builtin_amdgcn_mfma_f32_16x16x32_bf16(a0, bf1, acc[0][1], 0, 0, 0);
            acc[1][1] = __builtin_amdgcn_mfma_f32_16x16x32_bf16(a1, bf1, acc[1][1], 0, 0, 0);
        }
    }

    __syncthreads();   // buffers dead; reuse union as gu
#pragma unroll
    for (int i = 0; i < 2; i++)
#pragma unroll
        for (int j = 0; j < 2; j++)
#pragma unroll
            for (int r = 0; r < 4; r++) {
                int m = i * 16 + quad * 4 + r;
                int c = wid * 32 + j * 16 + lrow;
                u.gu[m * 132 + c] = acc[i][j][r];
            }
    __syncthreads();

#pragma unroll
    for (int ii = 0; ii < 8; ii++) {
        int o = ii * 256 + tid;
        int m = o >> 6, c = o & 63;
        if (m0 + m < count) {
            float g  = u.gu[m * 132 + c];
            float up = u.gu[m * 132 + 64 + c];
            float a  = g / (1.0f + expf(-g)) * up;
            act[(size_t)(abase + m0 + m) * I_DIM + n0 + c] = (__bf16)a;
        }
    }
}

// ---- GEMM2: out += w * (act @ dq(w2)^T) ----------------------------------
// M=32 x N=128, BK=32, async global_load_lds double-buffer
__global__ __launch_bounds__(256, 4) void gemm2_kernel(
    const __bf16* __restrict__ act,
    const float* __restrict__ w2,
    const float* __restrict__ w2s,
    const int* __restrict__ counts,
    const int* __restrict__ base,
    const int* __restrict__ tok_list,
    const float* __restrict__ wt_list,
    float* __restrict__ out)
{
    const int e = blockIdx.z;
    const int count = counts[e];
    const int m0 = blockIdx.y * 32;
    if (m0 >= count) return;
    const int n0 = blockIdx.x * 128;
    const int abase = base[e];

    __shared__ struct {
        float  Bf[2][128 * 32];
        __bf16 Ab[2][32 * 32];
    } s;
    __shared__ int   tokS[32];
    __shared__ float wtS[32];

    const int tid = threadIdx.x;
    if (tid < 32) {
        int r = m0 + tid;
        tokS[tid] = (r < count) ? tok_list[e * T_TOK + r] : tok_list[e * T_TOK];
        wtS[tid]  = (r < count) ? wt_list[e * T_TOK + r] : 0.f;
    }
    __syncthreads();

    const int wid = tid >> 6, lane = tid & 63, lrow = lane & 15, quad = lane >> 4;

    const int rB0 = wid * 32 + lrow, rB1 = rB0 + 16;
    float sc0[6], sc1[6];
#pragma unroll
    for (int kb = 0; kb < 6; kb++) {
        sc0[kb] = w2s[((size_t)e * H_DIM + n0 + rB0) * 6 + kb];
        sc1[kb] = w2s[((size_t)e * H_DIM + n0 + rB1) * 6 + kb];
    }

    const __bf16* pAst;
    {
        int r = (wid & 1) * 16 + (lane >> 2);
        int g = lane & 3;
        int gr = abase + m0 + r;
        if (gr > 2 * T_TOK - 1) gr = 2 * T_TOK - 1;
        pAst = act + (size_t)gr * I_DIM + ((g ^ (r & 3)) << 3);
    }
    const float* pBst[4];
#pragma unroll
    for (int i8 = 0; i8 < 4; i8++) {
        int r = wid * 32 + i8 * 8 + (lane >> 3);
        int g = lane & 7;
        pBst[i8] = w2 + ((size_t)e * H_DIM + n0 + r) * I_DIM + ((g ^ (r & 7)) << 2);
    }

    const int aoff0 = (lrow * 32 + ((quad ^ (lrow & 3)) << 3)) * 2;
    const int aoff1 = ((16 + lrow) * 32 + ((quad ^ (lrow & 3)) << 3)) * 2;
    const int b0off0 = (rB0 * 32 + (((2 * quad)     ^ (lrow & 7)) << 2)) * 4;
    const int b0off1 = (rB0 * 32 + (((2 * quad + 1) ^ (lrow & 7)) << 2)) * 4;
    const int b1off0 = (rB1 * 32 + (((2 * quad)     ^ (lrow & 7)) << 2)) * 4;
    const int b1off1 = (rB1 * 32 + (((2 * quad + 1) ^ (lrow & 7)) << 2)) * 4;

    f32x4 acc[2][2];
#pragma unroll
    for (int i = 0; i < 2; i++)
#pragma unroll
        for (int j = 0; j < 2; j++) { f32x4 z = {0.f, 0.f, 0.f, 0.f}; acc[i][j] = z; }

    auto issue = [&](int b, int k0) {
        if (wid < 2)
            gl2lds16(pAst + k0, &s.Ab[b][(wid * 16) * 32]);
#pragma unroll
        for (int i8 = 0; i8 < 4; i8++)
            gl2lds16(pBst[i8] + k0, &s.Bf[b][(wid * 32 + i8 * 8) * 32]);
    };
    issue(0, 0);

#pragma unroll
    for (int kb = 0; kb < 6; ++kb) {
#pragma unroll
        for (int t = 0; t < 4; ++t) {
            const int it = kb * 4 + t, b = it & 1;
            __syncthreads();
            if (it < 23) issue(b ^ 1, (it + 1) * 32);
            const char* Abase = (const char*)s.Ab[b];
            const char* Bbase = (const char*)s.Bf[b];
            bf16x8 a0 = *(const bf16x8*)(Abase + aoff0);
            bf16x8 a1 = *(const bf16x8*)(Abase + aoff1);
            f32x4 p00 = *(const f32x4*)(Bbase + b0off0);
            f32x4 p01 = *(const f32x4*)(Bbase + b0off1);
            f32x4 p10 = *(const f32x4*)(Bbase + b1off0);
            f32x4 p11 = *(const f32x4*)(Bbase + b1off1);
            bf16x8 bf0, bf1;
#pragma unroll
            for (int v = 0; v < 4; v++) {
                bf0[v]     = (__bf16)(p00[v] * sc0[kb]);
                bf0[4 + v] = (__bf16)(p01[v] * sc0[kb]);
                bf1[v]     = (__bf16)(p10[v] * sc1[kb]);
                bf1[4 + v] = (__bf16)(p11[v] * sc1[kb]);
            }
            acc[0][0] = __builtin_amdgcn_mfma_f32_16x16x32_bf16(a0, bf0, acc[0][0], 0, 0, 0);
            acc[1][0] = __builtin_amdgcn_mfma_f32_16x16x32_bf16(a1, bf0, acc[1][0], 0, 0, 0);
            acc[0][1] = __builtin_amdgcn_mfma_f32_16x16x32_bf16(a0, bf1, acc[0][1], 0, 0, 0);
            acc[1][1] = __builtin_amdgcn_mfma_f32_16x16x32_bf16(a1, bf1, acc[1][1], 0, 0, 0);
        }
    }

    // weighted atomic scatter
#pragma unroll
    for (int i = 0; i < 2; i++)
#pragma unroll
        for (int j = 0; j < 2; j++)
#pragma unroll
            for (int r = 0; r < 4; r++) {
                int m = i * 16 + quad * 4 + r;
                if (m0 + m < count) {
                    int h = n0 + wid * 32 + j * 16 + lrow;
                    atomicAdd(&out[(size_t)tokS[m] * H_DIM + h], wtS[m] * acc[i][j][r]);
                }
            }
}

extern "C" void kernel_launch(void* const* d_in, const int* in_sizes, int n_in,
                              void* d_out, int out_size, void* d_ws, size_t ws_size,
                              hipStream_t stream) {
    (void)in_sizes; (void)n_in; (void)out_size; (void)ws_size;
    const float* x      = (const float*)d_in[0];
    const float* logits = (const float*)d_in[1];
    const float* w13    = (const float*)d_in[2];
    const float* w13s   = (const float*)d_in[3];
    const float* w2     = (const float*)d_in[4];
    const float* w2s    = (const float*)d_in[5];
    float* out = (float*)d_out;

    char* ws = (char*)d_ws;
    int*    counts   = (int*)ws;                            // @0
    int*    base     = (int*)(ws + 128);                    // @128
    int*    tok_list = (int*)(ws + 256);                    // 32 KB
    float*  wt_list  = (float*)(ws + 256 + 32768);          // 32 KB
    __bf16* act      = (__bf16*)(ws + 256 + 65536);         // 3 MB, 16B-aligned
    __bf16* xbf      = (__bf16*)(ws + 256 + 65536 + 3145728); // 2 MB

    init_kernel<<<dim3(1024), 256, 0, stream>>>((float4*)out, counts,
                                                (const float4*)x, (bf16x4*)xbf);
    router_kernel<<<dim3(T_TOK / 256), 256, 0, stream>>>(logits, counts, tok_list, wt_list);
    scan_kernel<<<dim3(1), 64, 0, stream>>>(counts, base);
    gemm1_kernel<<<dim3(I_DIM / 64, T_TOK / 32, E_NUM), 256, 0, stream>>>(
        xbf, w13, w13s, counts, base, tok_list, act);
    gemm2_kernel<<<dim3(H_DIM / 128, T_TOK / 32, E_NUM), 256, 0, stream>>>(
        act, w2, w2s, counts, base, tok_list, wt_list, out);
}

// Round 4
// 162.629 us; speedup vs baseline: 1.4765x; 1.1671x over previous
//
#include <hip/hip_runtime.h>

#define T_TOK 1024
#define H_DIM 1024
#define I_DIM 768
#define E_NUM 8

// prep ranges (in 8-element groups)
#define G13 1572864   // 8*1536*1024/8
#define G2   786432   // 8*1024*768/8
#define GX   131072   // 1024*1024/8
#define GO   131072   // 1024*1024 floats / 8

typedef __bf16 bf16x8 __attribute__((ext_vector_type(8)));
typedef float  f32x4  __attribute__((ext_vector_type(4)));

__device__ inline void gl2lds16(const void* g, void* l) {
    __builtin_amdgcn_global_load_lds(
        (const __attribute__((address_space(1))) unsigned int*)g,
        (__attribute__((address_space(3))) unsigned int*)l, 16, 0, 0);
}

__device__ inline bf16x8 cvt8(float4 a, float4 b, float s) {
    bf16x8 o;
    o[0] = (__bf16)(a.x * s); o[1] = (__bf16)(a.y * s);
    o[2] = (__bf16)(a.z * s); o[3] = (__bf16)(a.w * s);
    o[4] = (__bf16)(b.x * s); o[5] = (__bf16)(b.y * s);
    o[6] = (__bf16)(b.z * s); o[7] = (__bf16)(b.w * s);
    return o;
}

// ---- prep: dequant w13/w2 -> bf16, convert x -> bf16, zero out -----------
__global__ __launch_bounds__(256) void prep_kernel(
    const float* __restrict__ w13, const float* __restrict__ w13s,
    const float* __restrict__ w2,  const float* __restrict__ w2s,
    const float* __restrict__ x,   float4* __restrict__ out4,
    __bf16* __restrict__ w13d, __bf16* __restrict__ w2d, __bf16* __restrict__ xbf)
{
    int g = blockIdx.x * 256 + threadIdx.x;
    if (g < G13) {
        int k8 = g & 127;               // 128 groups per 1024-k row
        int row = g >> 7;               // e*1536 + n
        float s = w13s[(row << 3) | (k8 >> 4)];
        const float4* src = (const float4*)w13 + (size_t)g * 2;
        *(bf16x8*)(w13d + (size_t)g * 8) = cvt8(src[0], src[1], s);
    } else if (g < G13 + G2) {
        int g2 = g - G13;
        unsigned row = (unsigned)g2 / 96u;   // e*1024 + h   (96 groups per 768-k row)
        int k8 = g2 - row * 96;
        float s = w2s[row * 6 + (k8 >> 4)];
        const float4* src = (const float4*)w2 + (size_t)g2 * 2;
        *(bf16x8*)(w2d + (size_t)g2 * 8) = cvt8(src[0], src[1], s);
    } else if (g < G13 + G2 + GX) {
        int gx = g - (G13 + G2);
        const float4* src = (const float4*)x + (size_t)gx * 2;
        *(bf16x8*)(xbf + (size_t)gx * 8) = cvt8(src[0], src[1], 1.0f);
    } else {
        int go = g - (G13 + G2 + GX);
        float4 z = make_float4(0.f, 0.f, 0.f, 0.f);
        out4[2 * go] = z; out4[2 * go + 1] = z;
    }
}

// ---- router: single block, LDS counters + scan ---------------------------
__global__ __launch_bounds__(1024) void router_kernel(
    const float* __restrict__ logits,
    int* __restrict__ counts, int* __restrict__ base,
    int* __restrict__ tok_list, float* __restrict__ wt_list)
{
    __shared__ int cnt[E_NUM];
    const int t = threadIdx.x;            // 1024 threads = 1024 tokens
    if (t < E_NUM) cnt[t] = 0;
    __syncthreads();
    float l[E_NUM];
#pragma unroll
    for (int e = 0; e < E_NUM; e++) l[e] = logits[t * E_NUM + e];
    int e0 = 0; float m0 = l[0];
#pragma unroll
    for (int e = 1; e < E_NUM; e++) if (l[e] > m0) { m0 = l[e]; e0 = e; }
    int e1 = -1; float m1 = -3e38f;
#pragma unroll
    for (int e = 0; e < E_NUM; e++) if (e != e0 && l[e] > m1) { m1 = l[e]; e1 = e; }
    float w0 = 1.0f / (1.0f + expf(m1 - m0));
    float w1 = 1.0f - w0;
    int p0 = atomicAdd(&cnt[e0], 1);
    tok_list[e0 * T_TOK + p0] = t;
    wt_list[e0 * T_TOK + p0] = w0;
    int p1 = atomicAdd(&cnt[e1], 1);
    tok_list[e1 * T_TOK + p1] = t;
    wt_list[e1 * T_TOK + p1] = w1;
    __syncthreads();
    if (t == 0) {
        int s = 0;
        for (int e = 0; e < E_NUM; e++) { base[e] = s; counts[e] = cnt[e]; s += cnt[e]; }
    }
}

// ---- GEMM1: gate_up = x_g @ w13d^T, + SiLU -------------------------------
// M=32 x N=128(64 gate+64 up), BK=64, bf16, async dbuf global_load_lds
__global__ __launch_bounds__(256, 3) void gemm1_kernel(
    const __bf16* __restrict__ xbf,
    const __bf16* __restrict__ w13d,
    const int* __restrict__ counts,
    const int* __restrict__ base,
    const int* __restrict__ tok_list,
    __bf16* __restrict__ act)
{
    const int e = blockIdx.z;
    const int count = counts[e];
    const int m0 = blockIdx.y * 32;
    if (m0 >= count) return;
    const int n0 = blockIdx.x * 64;
    const int abase = base[e];

    __shared__ union {
        struct {
            __bf16 Bs[2][128 * 64];   // 32 KB (row = 64 bf16 = 128B, lane-linear)
            __bf16 Ab[2][32 * 64];    // 8 KB
        } s;
        float gu[32 * 132];
    } u;
    __shared__ int tokS[32];

    const int tid = threadIdx.x;
    if (tid < 32) {
        int r = m0 + tid;
        tokS[tid] = (r < count) ? tok_list[e * T_TOK + r] : tok_list[e * T_TOK];
    }
    __syncthreads();

    const int wid = tid >> 6, lane = tid & 63, lrow = lane & 15, quad = lane >> 4;

    // staging sources (global-side XOR swizzle on 16B granules, 8/row)
    const int rA = wid * 8 + (lane >> 3);
    const __bf16* pAst = xbf + (size_t)tokS[rA] * H_DIM + (((lane & 7) ^ (rA & 7)) << 3);
    const __bf16* pBst[4];
#pragma unroll
    for (int i8 = 0; i8 < 4; i8++) {
        int r = wid * 32 + i8 * 8 + (lane >> 3);
        int n = (r < 64) ? (n0 + r) : (I_DIM + n0 + r - 64);
        pBst[i8] = w13d + ((size_t)e * 2 * I_DIM + n) * H_DIM + (((lane & 7) ^ (r & 7)) << 3);
    }

    // reader byte offsets: frag(row, k-granule kk*4+quad), row stride 128B
    int aoff[2][2], boff[2][2];
#pragma unroll
    for (int kk = 0; kk < 2; kk++) {
        int gph = ((kk * 4 + quad) ^ (lrow & 7)) << 4;
#pragma unroll
        for (int i = 0; i < 2; i++) {
            aoff[kk][i] = (i * 16 + lrow) * 128 + gph;
            boff[kk][i] = (wid * 32 + i * 16 + lrow) * 128 + gph;
        }
    }

    f32x4 acc[2][2];
#pragma unroll
    for (int i = 0; i < 2; i++)
#pragma unroll
        for (int j = 0; j < 2; j++) { f32x4 z = {0.f, 0.f, 0.f, 0.f}; acc[i][j] = z; }

    auto issue = [&](int b, int k0) {
        gl2lds16(pAst + k0, &u.s.Ab[b][(wid * 8) * 64]);
#pragma unroll
        for (int i8 = 0; i8 < 4; i8++)
            gl2lds16(pBst[i8] + k0, &u.s.Bs[b][(wid * 32 + i8 * 8) * 64]);
    };
    issue(0, 0);

#pragma unroll
    for (int it = 0; it < 16; ++it) {
        const int b = it & 1;
        __syncthreads();                     // drains vmcnt: buffer b ready
        if (it < 15) issue(b ^ 1, (it + 1) * 64);
        const char* Ab = (const char*)u.s.Ab[b];
        const char* Bb = (const char*)u.s.Bs[b];
#pragma unroll
        for (int kk = 0; kk < 2; kk++) {
            bf16x8 a0 = *(const bf16x8*)(Ab + aoff[kk][0]);
            bf16x8 a1 = *(const bf16x8*)(Ab + aoff[kk][1]);
            bf16x8 b0 = *(const bf16x8*)(Bb + boff[kk][0]);
            bf16x8 b1 = *(const bf16x8*)(Bb + boff[kk][1]);
            acc[0][0] = __builtin_amdgcn_mfma_f32_16x16x32_bf16(a0, b0, acc[0][0], 0, 0, 0);
            acc[1][0] = __builtin_amdgcn_mfma_f32_16x16x32_bf16(a1, b0, acc[1][0], 0, 0, 0);
            acc[0][1] = __builtin_amdgcn_mfma_f32_16x16x32_bf16(a0, b1, acc[0][1], 0, 0, 0);
            acc[1][1] = __builtin_amdgcn_mfma_f32_16x16x32_bf16(a1, b1, acc[1][1], 0, 0, 0);
        }
    }

    __syncthreads();   // staging dead; reuse union as gu
#pragma unroll
    for (int i = 0; i < 2; i++)
#pragma unroll
        for (int j = 0; j < 2; j++)
#pragma unroll
            for (int r = 0; r < 4; r++) {
                int m = i * 16 + quad * 4 + r;
                int c = wid * 32 + j * 16 + lrow;
                u.gu[m * 132 + c] = acc[i][j][r];
            }
    __syncthreads();

#pragma unroll
    for (int ii = 0; ii < 8; ii++) {
        int o = ii * 256 + tid;
        int m = o >> 6, c = o & 63;
        if (m0 + m < count) {
            float g  = u.gu[m * 132 + c];
            float up = u.gu[m * 132 + 64 + c];
            float a  = g / (1.0f + expf(-g)) * up;
            act[(size_t)(abase + m0 + m) * I_DIM + n0 + c] = (__bf16)a;
        }
    }
}

// ---- GEMM2: out += w * (act @ w2d^T) -------------------------------------
// M=32 x N=128, BK=64, bf16, async dbuf global_load_lds
__global__ __launch_bounds__(256, 3) void gemm2_kernel(
    const __bf16* __restrict__ act,
    const __bf16* __restrict__ w2d,
    const int* __restrict__ counts,
    const int* __restrict__ base,
    const int* __restrict__ tok_list,
    const float* __restrict__ wt_list,
    float* __restrict__ out)
{
    const int e = blockIdx.z;
    const int count = counts[e];
    const int m0 = blockIdx.y * 32;
    if (m0 >= count) return;
    const int n0 = blockIdx.x * 128;
    const int abase = base[e];

    __shared__ struct {
        __bf16 Bs[2][128 * 64];
        __bf16 Ab[2][32 * 64];
    } s;
    __shared__ int   tokS[32];
    __shared__ float wtS[32];

    const int tid = threadIdx.x;
    if (tid < 32) {
        int r = m0 + tid;
        tokS[tid] = (r < count) ? tok_list[e * T_TOK + r] : tok_list[e * T_TOK];
        wtS[tid]  = (r < count) ? wt_list[e * T_TOK + r] : 0.f;
    }
    __syncthreads();

    const int wid = tid >> 6, lane = tid & 63, lrow = lane & 15, quad = lane >> 4;

    const int rA = wid * 8 + (lane >> 3);
    int gr = abase + m0 + rA;
    if (gr > 2 * T_TOK - 1) gr = 2 * T_TOK - 1;
    const __bf16* pAst = act + (size_t)gr * I_DIM + (((lane & 7) ^ (rA & 7)) << 3);
    const __bf16* pBst[4];
#pragma unroll
    for (int i8 = 0; i8 < 4; i8++) {
        int r = wid * 32 + i8 * 8 + (lane >> 3);
        pBst[i8] = w2d + ((size_t)e * H_DIM + n0 + r) * I_DIM + (((lane & 7) ^ (r & 7)) << 3);
    }

    int aoff[2][2], boff[2][2];
#pragma unroll
    for (int kk = 0; kk < 2; kk++) {
        int gph = ((kk * 4 + quad) ^ (lrow & 7)) << 4;
#pragma unroll
        for (int i = 0; i < 2; i++) {
            aoff[kk][i] = (i * 16 + lrow) * 128 + gph;
            boff[kk][i] = (wid * 32 + i * 16 + lrow) * 128 + gph;
        }
    }

    f32x4 acc[2][2];
#pragma unroll
    for (int i = 0; i < 2; i++)
#pragma unroll
        for (int j = 0; j < 2; j++) { f32x4 z = {0.f, 0.f, 0.f, 0.f}; acc[i][j] = z; }

    auto issue = [&](int b, int k0) {
        gl2lds16(pAst + k0, &s.Ab[b][(wid * 8) * 64]);
#pragma unroll
        for (int i8 = 0; i8 < 4; i8++)
            gl2lds16(pBst[i8] + k0, &s.Bs[b][(wid * 32 + i8 * 8) * 64]);
    };
    issue(0, 0);

#pragma unroll
    for (int it = 0; it < 12; ++it) {        // K = 768
        const int b = it & 1;
        __syncthreads();
        if (it < 11) issue(b ^ 1, (it + 1) * 64);
        const char* Ab = (const char*)s.Ab[b];
        const char* Bb = (const char*)s.Bs[b];
#pragma unroll
        for (int kk = 0; kk < 2; kk++) {
            bf16x8 a0 = *(const bf16x8*)(Ab + aoff[kk][0]);
            bf16x8 a1 = *(const bf16x8*)(Ab + aoff[kk][1]);
            bf16x8 b0 = *(const bf16x8*)(Bb + boff[kk][0]);
            bf16x8 b1 = *(const bf16x8*)(Bb + boff[kk][1]);
            acc[0][0] = __builtin_amdgcn_mfma_f32_16x16x32_bf16(a0, b0, acc[0][0], 0, 0, 0);
            acc[1][0] = __builtin_amdgcn_mfma_f32_16x16x32_bf16(a1, b0, acc[1][0], 0, 0, 0);
            acc[0][1] = __builtin_amdgcn_mfma_f32_16x16x32_bf16(a0, b1, acc[0][1], 0, 0, 0);
            acc[1][1] = __builtin_amdgcn_mfma_f32_16x16x32_bf16(a1, b1, acc[1][1], 0, 0, 0);
        }
    }

    // weighted atomic scatter
#pragma unroll
    for (int i = 0; i < 2; i++)
#pragma unroll
        for (int j = 0; j < 2; j++)
#pragma unroll
            for (int r = 0; r < 4; r++) {
                int m = i * 16 + quad * 4 + r;
                if (m0 + m < count) {
                    int h = n0 + wid * 32 + j * 16 + lrow;
                    atomicAdd(&out[(size_t)tokS[m] * H_DIM + h], wtS[m] * acc[i][j][r]);
                }
            }
}

extern "C" void kernel_launch(void* const* d_in, const int* in_sizes, int n_in,
                              void* d_out, int out_size, void* d_ws, size_t ws_size,
                              hipStream_t stream) {
    (void)in_sizes; (void)n_in; (void)out_size; (void)ws_size;
    const float* x      = (const float*)d_in[0];
    const float* logits = (const float*)d_in[1];
    const float* w13    = (const float*)d_in[2];
    const float* w13s   = (const float*)d_in[3];
    const float* w2     = (const float*)d_in[4];
    const float* w2s    = (const float*)d_in[5];
    float* out = (float*)d_out;

    char* ws = (char*)d_ws;
    int*    counts   = (int*)ws;                              // @0
    int*    base     = (int*)(ws + 128);                      // @128
    int*    tok_list = (int*)(ws + 256);                      // 32 KB
    float*  wt_list  = (float*)(ws + 256 + 32768);            // 32 KB
    __bf16* act      = (__bf16*)(ws + 65792);                 // 3 MB
    __bf16* xbf      = (__bf16*)(ws + 65792 + 3145728);       // 2 MB
    __bf16* w13d     = (__bf16*)(ws + 65792 + 3145728 + 2097152);        // 25.2 MB
    __bf16* w2d      = (__bf16*)(ws + 65792 + 3145728 + 2097152 + 25165824); // 12.6 MB

    prep_kernel<<<dim3(10240), 256, 0, stream>>>(w13, w13s, w2, w2s, x,
                                                 (float4*)out, w13d, w2d, xbf);
    router_kernel<<<dim3(1), 1024, 0, stream>>>(logits, counts, base, tok_list, wt_list);
    gemm1_kernel<<<dim3(I_DIM / 64, T_TOK / 32, E_NUM), 256, 0, stream>>>(
        xbf, w13d, counts, base, tok_list, act);
    gemm2_kernel<<<dim3(H_DIM / 128, T_TOK / 32, E_NUM), 256, 0, stream>>>(
        act, w2d, counts, base, tok_list, wt_list, out);
}